// Round 5
// baseline (115.432 us; speedup 1.0000x reference)
//
#include <hip/hip_runtime.h>
#include <math.h>

#define NOUT 512
#define NIN  1024
#define HID  32
#define NB   256
#define TOPK 6
#define HSTR 40   // u16 row stride: 80 B = 16B-aligned for b128, bank-spread

typedef _Float16 f16x8 __attribute__((ext_vector_type(8)));
typedef float    f32x4 __attribute__((ext_vector_type(4)));

union HU  { _Float16 h; unsigned short u; };
union H4U { _Float16 h[4]; unsigned long long u; };
union H8U { _Float16 h[8]; uint4 u; };

__device__ __forceinline__ unsigned short f16bits(float v) {
    HU c; c.h = (_Float16)v; return c.u;
}

// ---------------- Kernel A: top-6 per output unit, one wave per o ----------------
// Mask row (1024 floats) lives in 16 regs/lane; 6 argmax rounds via shuffles.
// No LDS, no barriers. Writes indices to ws (8 ints per o, 6 used).
__global__ __launch_bounds__(256) void topk_kernel(
    const float* __restrict__ mask, int* __restrict__ sidx_out)
{
    const int o = (blockIdx.x << 2) | (threadIdx.x >> 6);
    const int l = threadIdx.x & 63;
    const float* mrow = mask + (size_t)o * NIN;

    float v[16];
#pragma unroll
    for (int j = 0; j < 16; ++j) v[j] = mrow[j * 64 + l];

#pragma unroll
    for (int it = 0; it < TOPK; ++it) {
        float bv = v[0]; int bi = l;
#pragma unroll
        for (int j = 1; j < 16; ++j)
            if (v[j] > bv) { bv = v[j]; bi = j * 64 + l; }
#pragma unroll
        for (int off = 32; off; off >>= 1) {
            float ov = __shfl_down(bv, off);
            int   oi = __shfl_down(bi, off);
            if (ov > bv) { bv = ov; bi = oi; }
        }
        bi = __shfl(bi, 0);                       // broadcast winner
#pragma unroll
        for (int j = 0; j < 16; ++j)
            if (bi == j * 64 + l) v[j] = -INFINITY;
        if (l == 0) sidx_out[o * 8 + it] = bi;
    }
}

// ---------------- MFMA helpers (verified round 4: absmax 0.0) ----------------
// 16x16x32 f16 layouts: A[m=lane&15][k=quad*8+j], B[k][n=lane&15],
// D: col=lane&15, row=quad*4+reg. Split-f16 (hi+lo) recovers fp32 precision.
template<int NMT>
__device__ __forceinline__ void mfma_layer(
    const unsigned short* WtHi, const unsigned short* WtLo,
    const unsigned short* HHi,  const unsigned short* HLo,
    int lane15, int quad, int wb, f32x4 acc[NMT][4])
{
    f16x8 aH[NMT], aL[NMT], bH[4], bL[4];
#pragma unroll
    for (int mt = 0; mt < NMT; ++mt) {
        int off = (mt * 16 + lane15) * HSTR + quad * 8;
        aH[mt] = *(const f16x8*)&WtHi[off];
        aL[mt] = *(const f16x8*)&WtLo[off];
    }
#pragma unroll
    for (int nt = 0; nt < 4; ++nt) {
        int off = (wb + nt * 16 + lane15) * HSTR + quad * 8;
        bH[nt] = *(const f16x8*)&HHi[off];
        bL[nt] = *(const f16x8*)&HLo[off];
    }
#pragma unroll
    for (int mt = 0; mt < NMT; ++mt)
#pragma unroll
        for (int nt = 0; nt < 4; ++nt) {
            acc[mt][nt] = __builtin_amdgcn_mfma_f32_16x16x32_f16(aH[mt], bH[nt], acc[mt][nt], 0, 0, 0);
            acc[mt][nt] = __builtin_amdgcn_mfma_f32_16x16x32_f16(aH[mt], bL[nt], acc[mt][nt], 0, 0, 0);
            acc[mt][nt] = __builtin_amdgcn_mfma_f32_16x16x32_f16(aL[mt], bH[nt], acc[mt][nt], 0, 0, 0);
            acc[mt][nt] = __builtin_amdgcn_mfma_f32_16x16x32_f16(aL[mt], bL[nt], acc[mt][nt], 0, 0, 0);
        }
}

__device__ __forceinline__ void store_h(
    unsigned short* HHi, unsigned short* HLo,
    int lane15, int quad, int wb, f32x4 acc[2][4])
{
#pragma unroll
    for (int mt = 0; mt < 2; ++mt)
#pragma unroll
        for (int nt = 0; nt < 4; ++nt) {
            H4U hi, lo;
#pragma unroll
            for (int r = 0; r < 4; ++r) {
                float v = acc[mt][nt][r];
                v = v > 0.0f ? v : 0.0f;
                _Float16 h = (_Float16)v;
                hi.h[r] = h;
                lo.h[r] = (_Float16)(v - (float)h);
            }
            int off = (wb + nt * 16 + lane15) * HSTR + mt * 16 + quad * 4;
            *(unsigned long long*)&HHi[off] = hi.u;
            *(unsigned long long*)&HLo[off] = lo.u;
        }
}

// ---------------- Kernel B: the 4-layer MLP, 2 blocks per o (128 batch each) ----
__global__ __launch_bounds__(128, 4) void mlp_kernel(
    const float* __restrict__ inputs,  // (B, IN)
    const float* __restrict__ W1,      // (OUT, IN, HID)
    const float* __restrict__ W2,      // (OUT, HID, HID)
    const float* __restrict__ W3,      // (OUT, HID, HID)
    const float* __restrict__ W4,      // (OUT, HID, 1)
    const int*   __restrict__ sidxg,   // (OUT, 8)
    float* __restrict__ out)           // (B, OUT)
{
    const int o    = blockIdx.x >> 1;
    const int half = (blockIdx.x & 1) << 7;   // batch base: 0 or 128
    const int t    = threadIdx.x;             // 0..127; local batch element
    const int l = t & 63, lane15 = l & 15, quad = l >> 4;
    const int wb = (t >> 6) << 6;             // wave's local-batch base: 0 or 64

    __shared__ __align__(16) unsigned short HtHi[128 * HSTR];
    __shared__ __align__(16) unsigned short HtLo[128 * HSTR];
    __shared__ __align__(16) unsigned short WHi[3][HID * HSTR];
    __shared__ __align__(16) unsigned short WLo[3][HID * HSTR];
    __shared__ __align__(16) unsigned short W4Hi[16 * HSTR];
    __shared__ __align__(16) unsigned short W4Lo[16 * HSTR];

    // ---- indices (wave-uniform scalars) ----
    int sj[TOPK];
#pragma unroll
    for (int j = 0; j < TOPK; ++j)
        sj[j] = __builtin_amdgcn_readfirstlane(sidxg[o * 8 + j]);

    // ---- issue input gathers immediately (longest-latency, scattered) ----
    const int bglob = half + t;
    float xg[TOPK];
#pragma unroll
    for (int j = 0; j < TOPK; ++j)
        xg[j] = inputs[(size_t)bglob * NIN + sj[j]];

    const float* W1g = W1 + (size_t)o * NIN * HID;
    const float* W2g = W2 + (size_t)o * HID * HID;
    const float* W3g = W3 + (size_t)o * HID * HID;
    const float* W4g = W4 + (size_t)o * HID;

    // ---- stage W1 (selected rows, transposed, zero-padded k>=6) ----
#pragma unroll
    for (int i = 0; i < 8; ++i) {
        int e = t + i * 128, m = e & 31, k = e >> 5;
        float v = (k < TOPK) ? W1g[(size_t)sj[k] * HID + m] : 0.0f;
        _Float16 h = (_Float16)v;
        WHi[0][m * HSTR + k] = f16bits(v);
        WLo[0][m * HSTR + k] = f16bits(v - (float)h);
    }
    // ---- stage W2/W3 transposed split-f16 ----
#pragma unroll
    for (int i = 0; i < 8; ++i) {
        int e = t + i * 128, m = e & 31, k = e >> 5;
        float v2 = W2g[e], v3 = W3g[e];
        _Float16 h2 = (_Float16)v2, h3 = (_Float16)v3;
        WHi[1][m * HSTR + k] = f16bits(v2);
        WLo[1][m * HSTR + k] = f16bits(v2 - (float)h2);
        WHi[2][m * HSTR + k] = f16bits(v3);
        WLo[2][m * HSTR + k] = f16bits(v3 - (float)h3);
    }
    // ---- stage W4 (row 0 = w4, rows 1..15 zero) ----
#pragma unroll
    for (int i = 0; i < 4; ++i) {
        int e = t + i * 128, m = e >> 5, k = e & 31;
        float v = (m == 0) ? W4g[k] : 0.0f;
        _Float16 h = (_Float16)v;
        W4Hi[m * HSTR + k] = f16bits(v);
        W4Lo[m * HSTR + k] = f16bits(v - (float)h);
    }

    // ---- write gathered inputs into H^T row t, zero-pad k=6..31 ----
    {
        H8U xh, xl;
#pragma unroll
        for (int j = 0; j < 8; ++j) { xh.h[j] = (_Float16)0.0f; xl.h[j] = (_Float16)0.0f; }
#pragma unroll
        for (int j = 0; j < TOPK; ++j) {
            float v = xg[j];
            _Float16 h = (_Float16)v;
            xh.h[j] = h;
            xl.h[j] = (_Float16)(v - (float)h);
        }
        *(uint4*)&HtHi[t * HSTR]      = xh.u;
        *(uint4*)&HtLo[t * HSTR]      = xl.u;
        uint4 z = make_uint4(0, 0, 0, 0);
        *(uint4*)&HtHi[t * HSTR + 8]  = z;
        *(uint4*)&HtHi[t * HSTR + 16] = z;
        *(uint4*)&HtHi[t * HSTR + 24] = z;
        *(uint4*)&HtLo[t * HSTR + 8]  = z;
        *(uint4*)&HtLo[t * HSTR + 16] = z;
        *(uint4*)&HtLo[t * HSTR + 24] = z;
    }
    __syncthreads();   // only barrier: staged data visible; layers are wave-private

    // ---- layers 1..3: H^T = relu(W^T · H^T) ----
    f32x4 acc[2][4];
#pragma unroll
    for (int L = 0; L < 3; ++L) {
#pragma unroll
        for (int mt = 0; mt < 2; ++mt)
#pragma unroll
            for (int nt = 0; nt < 4; ++nt) acc[mt][nt] = (f32x4){0.f, 0.f, 0.f, 0.f};
        mfma_layer<2>(&WHi[L][0], &WLo[L][0], HtHi, HtLo, lane15, quad, wb, acc);
        store_h(HtHi, HtLo, lane15, quad, wb, acc);
    }

    // ---- layer 4: z in D row 0 (quad==0, reg 0) ----
    f32x4 acc4[1][4];
#pragma unroll
    for (int nt = 0; nt < 4; ++nt) acc4[0][nt] = (f32x4){0.f, 0.f, 0.f, 0.f};
    mfma_layer<1>(W4Hi, W4Lo, HtHi, HtLo, lane15, quad, wb, acc4);

    if (quad == 0) {
#pragma unroll
        for (int nt = 0; nt < 4; ++nt) {
            int b = half + wb + nt * 16 + lane15;
            out[(size_t)b * NOUT + o] = (acc4[0][nt][0] >= 0.0f) ? 1.0f : -1.0f;
        }
    }
}

extern "C" void kernel_launch(void* const* d_in, const int* in_sizes, int n_in,
                              void* d_out, int out_size, void* d_ws, size_t ws_size,
                              hipStream_t stream) {
    const float* inputs = (const float*)d_in[0];
    const float* mask   = (const float*)d_in[1];
    const float* W1     = (const float*)d_in[2];
    const float* W2     = (const float*)d_in[3];
    const float* W3     = (const float*)d_in[4];
    const float* W4     = (const float*)d_in[5];
    float* out  = (float*)d_out;
    int*   sidx = (int*)d_ws;

    topk_kernel<<<dim3(NOUT / 4), dim3(256), 0, stream>>>(mask, sidx);
    mlp_kernel<<<dim3(NOUT * 2), dim3(128), 0, stream>>>(
        inputs, W1, W2, W3, W4, sidx, out);
}

// Round 6
// 111.034 us; speedup vs baseline: 1.0396x; 1.0396x over previous
//
#include <hip/hip_runtime.h>
#include <math.h>

#define NOUT 512
#define NIN  1024
#define HID  32
#define NB   256
#define TOPK 6
#define HSTR 40   // u16 row stride: 80 B = 16B-aligned for b128, bank-spread

typedef _Float16 f16x8 __attribute__((ext_vector_type(8)));
typedef float    f32x4 __attribute__((ext_vector_type(4)));

union HU  { _Float16 h; unsigned short u; };
union H4U { _Float16 h[4]; unsigned long long u; };
union H8U { _Float16 h[8]; uint4 u; };

__device__ __forceinline__ unsigned short f16bits(float v) {
    HU c; c.h = (_Float16)v; return c.u;
}

// ---------------- Kernel P: top-6 (blocks 0..127) + inputs transpose (128..191) ----
__global__ __launch_bounds__(256) void prep_kernel(
    const float* __restrict__ mask,     // (OUT, IN)
    const float* __restrict__ inputs,   // (B, IN)
    int*   __restrict__ sidx_out,       // (OUT, 8)
    float* __restrict__ inputsT)        // (IN, B)
{
    __shared__ float tile[64 * 65];
    const int t = threadIdx.x;

    if (blockIdx.x < 128) {
        // --- top-6 per output unit, one wave per o (verified R5: absmax 0.0) ---
        const int o = (blockIdx.x << 2) | (t >> 6);
        const int l = t & 63;
        const float* mrow = mask + (size_t)o * NIN;

        float v[16];
#pragma unroll
        for (int j = 0; j < 16; ++j) v[j] = mrow[j * 64 + l];

#pragma unroll
        for (int it = 0; it < TOPK; ++it) {
            float bv = v[0]; int bi = l;
#pragma unroll
            for (int j = 1; j < 16; ++j)
                if (v[j] > bv) { bv = v[j]; bi = j * 64 + l; }
#pragma unroll
            for (int off = 32; off; off >>= 1) {
                float ov = __shfl_down(bv, off);
                int   oi = __shfl_down(bi, off);
                if (ov > bv) { bv = ov; bi = oi; }
            }
            bi = __shfl(bi, 0);
#pragma unroll
            for (int j = 0; j < 16; ++j)
                if (bi == j * 64 + l) v[j] = -INFINITY;
            if (l == 0) sidx_out[o * 8 + it] = bi;
        }
    } else {
        // --- 64x64 tile transpose: inputsT[i][b] = inputs[b][i] ---
        const int bid = blockIdx.x - 128;     // 0..63
        const int rt = bid >> 2;              // i-tile 0..15
        const int ct = bid & 3;               // b-tile 0..3
        const int il = t & 63;                // inner (coalesced) index
        const int ql = t >> 6;                // 0..3

#pragma unroll
        for (int it = 0; it < 16; ++it) {
            int bl = ql + it * 4;             // 0..63
            tile[bl * 65 + il] = inputs[(size_t)(ct * 64 + bl) * NIN + rt * 64 + il];
        }
        __syncthreads();
#pragma unroll
        for (int it = 0; it < 16; ++it) {
            int iw = ql + it * 4;             // i within tile
            inputsT[(size_t)(rt * 64 + iw) * NB + ct * 64 + il] = tile[il * 65 + iw];
        }
    }
}

// ---------------- MFMA helpers (verified R4/R5: absmax 0.0) ----------------
// 16x16x32 f16 layouts: A[m=lane&15][k=quad*8+j], B[k][n=lane&15],
// D: col=lane&15, row=quad*4+reg. Split-f16 (hi+lo) recovers fp32 precision.
template<int NMT>
__device__ __forceinline__ void mfma_layer(
    const unsigned short* WtHi, const unsigned short* WtLo,
    const unsigned short* HHi,  const unsigned short* HLo,
    int lane15, int quad, int wb, f32x4 acc[NMT][4])
{
    f16x8 aH[NMT], aL[NMT], bH[4], bL[4];
#pragma unroll
    for (int mt = 0; mt < NMT; ++mt) {
        int off = (mt * 16 + lane15) * HSTR + quad * 8;
        aH[mt] = *(const f16x8*)&WtHi[off];
        aL[mt] = *(const f16x8*)&WtLo[off];
    }
#pragma unroll
    for (int nt = 0; nt < 4; ++nt) {
        int off = (wb + nt * 16 + lane15) * HSTR + quad * 8;
        bH[nt] = *(const f16x8*)&HHi[off];
        bL[nt] = *(const f16x8*)&HLo[off];
    }
#pragma unroll
    for (int mt = 0; mt < NMT; ++mt)
#pragma unroll
        for (int nt = 0; nt < 4; ++nt) {
            acc[mt][nt] = __builtin_amdgcn_mfma_f32_16x16x32_f16(aH[mt], bH[nt], acc[mt][nt], 0, 0, 0);
            acc[mt][nt] = __builtin_amdgcn_mfma_f32_16x16x32_f16(aH[mt], bL[nt], acc[mt][nt], 0, 0, 0);
            acc[mt][nt] = __builtin_amdgcn_mfma_f32_16x16x32_f16(aL[mt], bH[nt], acc[mt][nt], 0, 0, 0);
            acc[mt][nt] = __builtin_amdgcn_mfma_f32_16x16x32_f16(aL[mt], bL[nt], acc[mt][nt], 0, 0, 0);
        }
}

__device__ __forceinline__ void store_h(
    unsigned short* HHi, unsigned short* HLo,
    int lane15, int quad, int wb, f32x4 acc[2][4])
{
#pragma unroll
    for (int mt = 0; mt < 2; ++mt)
#pragma unroll
        for (int nt = 0; nt < 4; ++nt) {
            H4U hi, lo;
#pragma unroll
            for (int r = 0; r < 4; ++r) {
                float v = acc[mt][nt][r];
                v = v > 0.0f ? v : 0.0f;
                _Float16 h = (_Float16)v;
                hi.h[r] = h;
                lo.h[r] = (_Float16)(v - (float)h);
            }
            int off = (wb + nt * 16 + lane15) * HSTR + mt * 16 + quad * 4;
            *(unsigned long long*)&HHi[off] = hi.u;
            *(unsigned long long*)&HLo[off] = lo.u;
        }
}

// ---------------- Kernel B: 4-layer MLP, 1 block per o, 256 batch ----------------
__global__ __launch_bounds__(256, 2) void mlp_kernel(
    const float* __restrict__ inputsT, // (IN, B) from prep
    const float* __restrict__ W1,      // (OUT, IN, HID)
    const float* __restrict__ W2,      // (OUT, HID, HID)
    const float* __restrict__ W3,      // (OUT, HID, HID)
    const float* __restrict__ W4,      // (OUT, HID, 1)
    const int*   __restrict__ sidxg,   // (OUT, 8)
    float* __restrict__ out)           // (B, OUT)
{
    const int o = blockIdx.x;
    const int t = threadIdx.x;                // = batch element b
    const int l = t & 63, lane15 = l & 15, quad = l >> 4;
    const int wb = (t >> 6) << 6;             // wave's batch base: 0/64/128/192

    __shared__ __align__(16) unsigned short HtHi[NB * HSTR];
    __shared__ __align__(16) unsigned short HtLo[NB * HSTR];
    __shared__ __align__(16) unsigned short WHi[3][HID * HSTR];
    __shared__ __align__(16) unsigned short WLo[3][HID * HSTR];
    __shared__ __align__(16) unsigned short W4Hi[16 * HSTR];
    __shared__ __align__(16) unsigned short W4Lo[16 * HSTR];

    // ---- indices (wave-uniform scalars) ----
    int sj[TOPK];
#pragma unroll
    for (int j = 0; j < TOPK; ++j)
        sj[j] = __builtin_amdgcn_readfirstlane(sidxg[o * 8 + j]);

    // ---- gather inputs: now COALESCED rows of inputsT ----
    float xg[TOPK];
#pragma unroll
    for (int j = 0; j < TOPK; ++j)
        xg[j] = inputsT[(size_t)sj[j] * NB + t];

    const float* W1g = W1 + (size_t)o * NIN * HID;
    const float* W2g = W2 + (size_t)o * HID * HID;
    const float* W3g = W3 + (size_t)o * HID * HID;
    const float* W4g = W4 + (size_t)o * HID;

    // ---- stage W1: thread -> (m = t>>3, kg = t&7), packed b64 write ----
    {
        const int m = t >> 3, kg = t & 7;
        H4U hi, lo;
#pragma unroll
        for (int r = 0; r < 4; ++r) {
            int k = kg * 4 + r;
            float v = (k < TOPK) ? W1g[(size_t)sj[k] * HID + m] : 0.0f;
            _Float16 h = (_Float16)v;
            hi.h[r] = h;
            lo.h[r] = (_Float16)(v - (float)h);
        }
        *(unsigned long long*)&WHi[0][m * HSTR + kg * 4] = hi.u;
        *(unsigned long long*)&WLo[0][m * HSTR + kg * 4] = lo.u;
    }

    // ---- stage W2/W3: float4 global loads, transposed split-f16 LDS ----
    {
        const int k = t >> 3, m0 = (t & 7) * 4;
        float4 v2 = *(const float4*)&W2g[t * 4];
        float4 v3 = *(const float4*)&W3g[t * 4];
        const float a2[4] = {v2.x, v2.y, v2.z, v2.w};
        const float a3[4] = {v3.x, v3.y, v3.z, v3.w};
#pragma unroll
        for (int r = 0; r < 4; ++r) {
            _Float16 h2 = (_Float16)a2[r], h3 = (_Float16)a3[r];
            WHi[1][(m0 + r) * HSTR + k] = f16bits(a2[r]);
            WLo[1][(m0 + r) * HSTR + k] = f16bits(a2[r] - (float)h2);
            WHi[2][(m0 + r) * HSTR + k] = f16bits(a3[r]);
            WLo[2][(m0 + r) * HSTR + k] = f16bits(a3[r] - (float)h3);
        }
    }

    // ---- stage W4: row 0 = w4 (cols 0..31), rest zero ----
    if (t < HSTR) {
        float v = (t < HID) ? W4g[t] : 0.0f;
        _Float16 h = (_Float16)v;
        W4Hi[t] = f16bits(v);
        W4Lo[t] = f16bits(v - (float)h);
    }
    for (int idx = HSTR + t; idx < 16 * HSTR; idx += 256) {
        W4Hi[idx] = 0;
        W4Lo[idx] = 0;
    }

    // ---- write gathered inputs into H^T row t, zero-pad k=6..31 ----
    {
        H8U xh, xl;
#pragma unroll
        for (int j = 0; j < 8; ++j) { xh.h[j] = (_Float16)0.0f; xl.h[j] = (_Float16)0.0f; }
#pragma unroll
        for (int j = 0; j < TOPK; ++j) {
            float v = xg[j];
            _Float16 h = (_Float16)v;
            xh.h[j] = h;
            xl.h[j] = (_Float16)(v - (float)h);
        }
        *(uint4*)&HtHi[t * HSTR]      = xh.u;
        *(uint4*)&HtLo[t * HSTR]      = xl.u;
        uint4 z = make_uint4(0, 0, 0, 0);
        *(uint4*)&HtHi[t * HSTR + 8]  = z;
        *(uint4*)&HtHi[t * HSTR + 16] = z;
        *(uint4*)&HtHi[t * HSTR + 24] = z;
        *(uint4*)&HtLo[t * HSTR + 8]  = z;
        *(uint4*)&HtLo[t * HSTR + 16] = z;
        *(uint4*)&HtLo[t * HSTR + 24] = z;
    }
    __syncthreads();   // only barrier; layers are wave-private after this

    // ---- layers 1..3: H^T = relu(W^T · H^T) ----
    f32x4 acc[2][4];
#pragma unroll
    for (int L = 0; L < 3; ++L) {
#pragma unroll
        for (int mt = 0; mt < 2; ++mt)
#pragma unroll
            for (int nt = 0; nt < 4; ++nt) acc[mt][nt] = (f32x4){0.f, 0.f, 0.f, 0.f};
        mfma_layer<2>(&WHi[L][0], &WLo[L][0], HtHi, HtLo, lane15, quad, wb, acc);
        store_h(HtHi, HtLo, lane15, quad, wb, acc);
    }

    // ---- layer 4: z in D row 0 (quad==0, reg 0) ----
    f32x4 acc4[1][4];
#pragma unroll
    for (int nt = 0; nt < 4; ++nt) acc4[0][nt] = (f32x4){0.f, 0.f, 0.f, 0.f};
    mfma_layer<1>(W4Hi, W4Lo, HtHi, HtLo, lane15, quad, wb, acc4);

    if (quad == 0) {
#pragma unroll
        for (int nt = 0; nt < 4; ++nt) {
            int b = wb + nt * 16 + lane15;
            out[(size_t)b * NOUT + o] = (acc4[0][nt][0] >= 0.0f) ? 1.0f : -1.0f;
        }
    }
}

extern "C" void kernel_launch(void* const* d_in, const int* in_sizes, int n_in,
                              void* d_out, int out_size, void* d_ws, size_t ws_size,
                              hipStream_t stream) {
    const float* inputs = (const float*)d_in[0];
    const float* mask   = (const float*)d_in[1];
    const float* W1     = (const float*)d_in[2];
    const float* W2     = (const float*)d_in[3];
    const float* W3     = (const float*)d_in[4];
    const float* W4     = (const float*)d_in[5];
    float* out  = (float*)d_out;
    int*   sidx = (int*)d_ws;
    float* inputsT = (float*)((char*)d_ws + 16384);   // 1 MB at ws+16K

    prep_kernel<<<dim3(192), dim3(256), 0, stream>>>(mask, inputs, sidx, inputsT);
    mlp_kernel<<<dim3(NOUT), dim3(256), 0, stream>>>(
        inputsT, W1, W2, W3, W4, sidx, out);
}